// Round 1
// baseline (2321.290 us; speedup 1.0000x reference)
//
#include <hip/hip_runtime.h>

#define N_NODES 100000
#define N_EDGES 1600000
#define N_GRAPH 1024

__device__ __forceinline__ float sigm(float z) { return 1.0f / (1.0f + __expf(-z)); }

// ---------------- Layer 1: ResGated(F_IN=1 -> 32) ----------------
// h1_acc[i][:] = x_i * Wskip + b   (atomics accumulate messages on top)
__global__ __launch_bounds__(256) void k_node1(
    const float* __restrict__ x, const float* __restrict__ Wskip,
    const float* __restrict__ b, float* __restrict__ h1)
{
    int tid = blockIdx.x * 256 + threadIdx.x;
    if (tid >= N_NODES * 8) return;
    int i = tid >> 3, l = tid & 7;
    float xv = x[i];
    float4 w  = ((const float4*)Wskip)[l];
    float4 bb = ((const float4*)b)[l];
    float4 o = make_float4(fmaf(xv, w.x, bb.x), fmaf(xv, w.y, bb.y),
                           fmaf(xv, w.z, bb.z), fmaf(xv, w.w, bb.w));
    ((float4*)(h1 + (size_t)i * 32))[l] = o;
}

// msg = sigmoid(k[dst]+q[src]) * v[src], with k/q/v rank-1 in x (F_IN=1).
__global__ __launch_bounds__(256) void k_edge1(
    const int* __restrict__ ei, const float* __restrict__ x,
    const float* __restrict__ Wk, const float* __restrict__ bk,
    const float* __restrict__ Wq, const float* __restrict__ bq,
    const float* __restrict__ Wv, const float* __restrict__ bv,
    float* __restrict__ acc, float* __restrict__ deg)
{
    int tid = blockIdx.x * 256 + threadIdx.x;
    if (tid >= N_EDGES * 8) return;
    int e = tid >> 3, l = tid & 7;
    int s = ei[e], d = ei[N_EDGES + e];
    float xs = x[s], xd = x[d];
    float4 wk = ((const float4*)Wk)[l], bk4 = ((const float4*)bk)[l];
    float4 wq = ((const float4*)Wq)[l], bq4 = ((const float4*)bq)[l];
    float4 wv = ((const float4*)Wv)[l], bv4 = ((const float4*)bv)[l];
    float m0 = sigm(fmaf(xd, wk.x, bk4.x) + fmaf(xs, wq.x, bq4.x)) * fmaf(xs, wv.x, bv4.x);
    float m1 = sigm(fmaf(xd, wk.y, bk4.y) + fmaf(xs, wq.y, bq4.y)) * fmaf(xs, wv.y, bv4.y);
    float m2 = sigm(fmaf(xd, wk.z, bk4.z) + fmaf(xs, wq.z, bq4.z)) * fmaf(xs, wv.z, bv4.z);
    float m3 = sigm(fmaf(xd, wk.w, bk4.w) + fmaf(xs, wq.w, bq4.w)) * fmaf(xs, wv.w, bv4.w);
    float* ap = acc + (size_t)d * 32 + l * 4;
    atomicAdd(ap + 0, m0);
    atomicAdd(ap + 1, m1);
    atomicAdd(ap + 2, m2);
    atomicAdd(ap + 3, m3);
    if (l == 0) atomicAdd(&deg[d], 1.0f);
}

// dot of h[32] against 4 consecutive LDS weight columns (stride = fout)
__device__ __forceinline__ float4 dot4(const float* __restrict__ h,
                                       const float* __restrict__ Wcol, int stride)
{
    float4 a = make_float4(0.f, 0.f, 0.f, 0.f);
#pragma unroll
    for (int k = 0; k < 32; k++) {
        float4 w = *(const float4*)(Wcol + k * stride);
        float hk = h[k];
        a.x = fmaf(hk, w.x, a.x);
        a.y = fmaf(hk, w.y, a.y);
        a.z = fmaf(hk, w.z, a.z);
        a.w = fmaf(hk, w.w, a.w);
    }
    return a;
}

// ---------------- Layer 2: FiLM node-side ----------------
// h = relu(h1); skip2 = relu(gamma_s*(h@Wls)+beta_s); bg2 = h@Wfilm+bfilm; xl = h@Wlin
__global__ __launch_bounds__(256) void k_node2(
    const float* __restrict__ h1,
    const float* __restrict__ Wlin, const float* __restrict__ Wfilm,
    const float* __restrict__ bfilm, const float* __restrict__ Wls,
    const float* __restrict__ Wfs,
    float* __restrict__ skip2, float* __restrict__ bg2, float* __restrict__ xl)
{
    __shared__ float sWlin[32 * 32], sWfilm[32 * 64], sWls[32 * 32], sWfs[32 * 64];
    int t = threadIdx.x;
    for (int idx = t; idx < 1024; idx += 256) sWlin[idx] = Wlin[idx];
    for (int idx = t; idx < 2048; idx += 256) sWfilm[idx] = Wfilm[idx];
    for (int idx = t; idx < 1024; idx += 256) sWls[idx] = Wls[idx];
    for (int idx = t; idx < 2048; idx += 256) sWfs[idx] = Wfs[idx];
    __syncthreads();

    int tid = blockIdx.x * 256 + t;
    if (tid >= N_NODES * 8) return;
    int i = tid >> 3, l = tid & 7;

    float h[32];
    const float4* hp = (const float4*)(h1 + (size_t)i * 32);
#pragma unroll
    for (int j = 0; j < 8; j++) {
        float4 v = hp[j];
        h[4 * j + 0] = fmaxf(v.x, 0.f);
        h[4 * j + 1] = fmaxf(v.y, 0.f);
        h[4 * j + 2] = fmaxf(v.z, 0.f);
        h[4 * j + 3] = fmaxf(v.w, 0.f);
    }

    // skip path
    float4 bs = dot4(h, sWfs + l * 4, 64);        // beta_s cols 0..31
    float4 gs = dot4(h, sWfs + 32 + l * 4, 64);   // gamma_s cols 32..63
    float4 ls = dot4(h, sWls + l * 4, 32);
    float4 sk = make_float4(fmaxf(fmaf(gs.x, ls.x, bs.x), 0.f),
                            fmaxf(fmaf(gs.y, ls.y, bs.y), 0.f),
                            fmaxf(fmaf(gs.z, ls.z, bs.z), 0.f),
                            fmaxf(fmaf(gs.w, ls.w, bs.w), 0.f));
    ((float4*)(skip2 + (size_t)i * 32))[l] = sk;

    // film beta|gamma (64 wide)
    float4 bf0 = ((const float4*)bfilm)[l * 2];
    float4 bf1 = ((const float4*)bfilm)[l * 2 + 1];
    float4 f0 = dot4(h, sWfilm + l * 8, 64);
    float4 f1 = dot4(h, sWfilm + l * 8 + 4, 64);
    f0.x += bf0.x; f0.y += bf0.y; f0.z += bf0.z; f0.w += bf0.w;
    f1.x += bf1.x; f1.y += bf1.y; f1.z += bf1.z; f1.w += bf1.w;
    float4* bgp = (float4*)(bg2 + (size_t)i * 64);
    bgp[l * 2] = f0;
    bgp[l * 2 + 1] = f1;

    // xl
    float4 xo = dot4(h, sWlin + l * 4, 32);
    ((float4*)(xl + (size_t)i * 32))[l] = xo;
}

// msg = relu(gamma[dst]*xl[src] + beta[dst]) -> acc2[dst]
__global__ __launch_bounds__(256) void k_edge2(
    const int* __restrict__ ei, const float* __restrict__ bg2,
    const float* __restrict__ xl, float* __restrict__ acc2)
{
    int tid = blockIdx.x * 256 + threadIdx.x;
    if (tid >= N_EDGES * 8) return;
    int e = tid >> 3, l = tid & 7;
    int s = ei[e], d = ei[N_EDGES + e];
    float4 xs = ((const float4*)(xl + (size_t)s * 32))[l];
    float4 be = ((const float4*)(bg2 + (size_t)d * 64))[l];
    float4 ga = ((const float4*)(bg2 + (size_t)d * 64 + 32))[l];
    float m0 = fmaxf(fmaf(ga.x, xs.x, be.x), 0.f);
    float m1 = fmaxf(fmaf(ga.y, xs.y, be.y), 0.f);
    float m2 = fmaxf(fmaf(ga.z, xs.z, be.z), 0.f);
    float m3 = fmaxf(fmaf(ga.w, xs.w, be.w), 0.f);
    float* ap = acc2 + (size_t)d * 32 + l * 4;
    atomicAdd(ap + 0, m0);
    atomicAdd(ap + 1, m1);
    atomicAdd(ap + 2, m2);
    atomicAdd(ap + 3, m3);
}

// ---------------- Layer 3 node-side ----------------
// h2 = relu(skip2 + acc2/max(deg,1)); k3/q3/v3 = h2@W+b; acc3 = h2@Wskip+b
__global__ __launch_bounds__(256) void k_node3(
    const float* __restrict__ skip2, const float* __restrict__ acc2,
    const float* __restrict__ deg,
    const float* __restrict__ Wk, const float* __restrict__ bk,
    const float* __restrict__ Wq, const float* __restrict__ bq,
    const float* __restrict__ Wv, const float* __restrict__ bv,
    const float* __restrict__ Wskip, const float* __restrict__ b,
    float* __restrict__ k3, float* __restrict__ q3, float* __restrict__ v3,
    float* __restrict__ acc3)
{
    __shared__ float sWk[1024], sWq[1024], sWv[1024], sWs[1024];
    int t = threadIdx.x;
    for (int idx = t; idx < 1024; idx += 256) {
        sWk[idx] = Wk[idx];
        sWq[idx] = Wq[idx];
        sWv[idx] = Wv[idx];
        sWs[idx] = Wskip[idx];
    }
    __syncthreads();

    int tid = blockIdx.x * 256 + t;
    if (tid >= N_NODES * 8) return;
    int i = tid >> 3, l = tid & 7;

    float inv = 1.0f / fmaxf(deg[i], 1.0f);
    float h[32];
    const float4* ap = (const float4*)(acc2 + (size_t)i * 32);
    const float4* sp = (const float4*)(skip2 + (size_t)i * 32);
#pragma unroll
    for (int j = 0; j < 8; j++) {
        float4 a = ap[j];
        float4 s = sp[j];
        h[4 * j + 0] = fmaxf(fmaf(a.x, inv, s.x), 0.f);
        h[4 * j + 1] = fmaxf(fmaf(a.y, inv, s.y), 0.f);
        h[4 * j + 2] = fmaxf(fmaf(a.z, inv, s.z), 0.f);
        h[4 * j + 3] = fmaxf(fmaf(a.w, inv, s.w), 0.f);
    }

    float4 bk4 = ((const float4*)bk)[l];
    float4 bq4 = ((const float4*)bq)[l];
    float4 bv4 = ((const float4*)bv)[l];
    float4 bb4 = ((const float4*)b)[l];

    float4 kk = dot4(h, sWk + l * 4, 32);
    kk.x += bk4.x; kk.y += bk4.y; kk.z += bk4.z; kk.w += bk4.w;
    ((float4*)(k3 + (size_t)i * 32))[l] = kk;

    float4 qq = dot4(h, sWq + l * 4, 32);
    qq.x += bq4.x; qq.y += bq4.y; qq.z += bq4.z; qq.w += bq4.w;
    ((float4*)(q3 + (size_t)i * 32))[l] = qq;

    float4 vv = dot4(h, sWv + l * 4, 32);
    vv.x += bv4.x; vv.y += bv4.y; vv.z += bv4.z; vv.w += bv4.w;
    ((float4*)(v3 + (size_t)i * 32))[l] = vv;

    float4 ss = dot4(h, sWs + l * 4, 32);
    ss.x += bb4.x; ss.y += bb4.y; ss.z += bb4.z; ss.w += bb4.w;
    ((float4*)(acc3 + (size_t)i * 32))[l] = ss;
}

// msg = sigmoid(k3[dst]+q3[src]) * v3[src] -> acc3[dst]
__global__ __launch_bounds__(256) void k_edge3(
    const int* __restrict__ ei,
    const float* __restrict__ k3, const float* __restrict__ q3,
    const float* __restrict__ v3, float* __restrict__ acc3)
{
    int tid = blockIdx.x * 256 + threadIdx.x;
    if (tid >= N_EDGES * 8) return;
    int e = tid >> 3, l = tid & 7;
    int s = ei[e], d = ei[N_EDGES + e];
    float4 kk = ((const float4*)(k3 + (size_t)d * 32))[l];
    float4 qq = ((const float4*)(q3 + (size_t)s * 32))[l];
    float4 vv = ((const float4*)(v3 + (size_t)s * 32))[l];
    float m0 = sigm(kk.x + qq.x) * vv.x;
    float m1 = sigm(kk.y + qq.y) * vv.y;
    float m2 = sigm(kk.z + qq.z) * vv.z;
    float m3 = sigm(kk.w + qq.w) * vv.w;
    float* ap = acc3 + (size_t)d * 32 + l * 4;
    atomicAdd(ap + 0, m0);
    atomicAdd(ap + 1, m1);
    atomicAdd(ap + 2, m2);
    atomicAdd(ap + 3, m3);
}

// ---------------- global mean pool ----------------
__global__ __launch_bounds__(256) void k_pool(
    const float* __restrict__ h3, const int* __restrict__ batch,
    float* __restrict__ gsum, float* __restrict__ gcnt)
{
    int tid = blockIdx.x * 256 + threadIdx.x;
    if (tid >= N_NODES * 8) return;
    int i = tid >> 3, l = tid & 7;
    int g = batch[i];
    float4 v = ((const float4*)(h3 + (size_t)i * 32))[l];
    float* gp = gsum + (size_t)g * 32 + l * 4;
    atomicAdd(gp + 0, v.x);
    atomicAdd(gp + 1, v.y);
    atomicAdd(gp + 2, v.z);
    atomicAdd(gp + 3, v.w);
    if (l == 0) atomicAdd(&gcnt[g], 1.0f);
}

// out[g,c] = dot(gsum[g], linW[:,c]) / max(cnt,1) + linb[c]
__global__ __launch_bounds__(256) void k_final(
    const float* __restrict__ gsum, const float* __restrict__ gcnt,
    const float* __restrict__ linW, const float* __restrict__ linb,
    float* __restrict__ out)
{
    int tid = blockIdx.x * 256 + threadIdx.x;
    if (tid >= N_GRAPH * 10) return;
    int g = tid / 10, c = tid % 10;
    float inv = 1.0f / fmaxf(gcnt[g], 1.0f);
    const float* gr = gsum + (size_t)g * 32;
    float a = 0.f;
#pragma unroll
    for (int k = 0; k < 32; k++) a = fmaf(gr[k], linW[k * 10 + c], a);
    out[tid] = fmaf(a, inv, linb[c]);
}

extern "C" void kernel_launch(void* const* d_in, const int* in_sizes, int n_in,
                              void* d_out, int out_size, void* d_ws, size_t ws_size,
                              hipStream_t stream)
{
    const float* x      = (const float*)d_in[0];
    const int*   ei     = (const int*)d_in[1];
    const int*   batch  = (const int*)d_in[2];
    // d_in[3] = num_graphs (compile-time constant 1024)
    const float* c1_Wk   = (const float*)d_in[4];
    const float* c1_bk   = (const float*)d_in[5];
    const float* c1_Wq   = (const float*)d_in[6];
    const float* c1_bq   = (const float*)d_in[7];
    const float* c1_Wv   = (const float*)d_in[8];
    const float* c1_bv   = (const float*)d_in[9];
    const float* c1_Wsk  = (const float*)d_in[10];
    const float* c1_b    = (const float*)d_in[11];
    const float* c2_Wlin = (const float*)d_in[12];
    const float* c2_Wfilm= (const float*)d_in[13];
    const float* c2_bfilm= (const float*)d_in[14];
    const float* c2_Wls  = (const float*)d_in[15];
    const float* c2_Wfs  = (const float*)d_in[16];
    const float* c3_Wk   = (const float*)d_in[17];
    const float* c3_bk   = (const float*)d_in[18];
    const float* c3_Wq   = (const float*)d_in[19];
    const float* c3_bq   = (const float*)d_in[20];
    const float* c3_Wv   = (const float*)d_in[21];
    const float* c3_bv   = (const float*)d_in[22];
    const float* c3_Wsk  = (const float*)d_in[23];
    const float* c3_b    = (const float*)d_in[24];
    const float* lin_W   = (const float*)d_in[25];
    const float* lin_b   = (const float*)d_in[26];
    float* out = (float*)d_out;

    const size_t N = N_NODES, G = N_GRAPH;
    float* ws = (float*)d_ws;
    float* A   = ws;                 // N*32  h1_acc   -> reused as k3
    float* C   = A + N * 32;         // N*32  xl       -> reused as q3
    float* B   = C + N * 32;         // N*64  beta|gamma -> reused as [v3 | acc3]
    float* Dm  = B + N * 64;         // N*32  skip2
    float* Ez  = Dm + N * 32;        // N*32  acc2   (zeroed)
    float* F   = Ez + N * 32;        // N     deg    (zeroed)
    float* K   = F + N;              // G*32  gsum   (zeroed)
    float* L   = K + G * 32;         // G     gcnt   (zeroed)

    size_t zbytes = (size_t)(N * 32 + N + G * 32 + G) * sizeof(float);
    hipMemsetAsync(Ez, 0, zbytes, stream);

    const int TB = 256;
    int gNode = (N_NODES * 8 + TB - 1) / TB;   // 3125
    int gEdge = (N_EDGES * 8 + TB - 1) / TB;   // 50000
    int gFin  = (N_GRAPH * 10 + TB - 1) / TB;  // 40

    // Layer 1
    k_node1<<<gNode, TB, 0, stream>>>(x, c1_Wsk, c1_b, A);
    k_edge1<<<gEdge, TB, 0, stream>>>(ei, x, c1_Wk, c1_bk, c1_Wq, c1_bq,
                                      c1_Wv, c1_bv, A, F);
    // Layer 2 (FiLM)
    k_node2<<<gNode, TB, 0, stream>>>(A, c2_Wlin, c2_Wfilm, c2_bfilm,
                                      c2_Wls, c2_Wfs, Dm, B, C);
    k_edge2<<<gEdge, TB, 0, stream>>>(ei, B, C, Ez);
    // Layer 3 (ResGated)
    float* k3 = A;
    float* q3 = C;
    float* v3 = B;
    float* acc3 = B + N * 32;
    k_node3<<<gNode, TB, 0, stream>>>(Dm, Ez, F,
                                      c3_Wk, c3_bk, c3_Wq, c3_bq,
                                      c3_Wv, c3_bv, c3_Wsk, c3_b,
                                      k3, q3, v3, acc3);
    k_edge3<<<gEdge, TB, 0, stream>>>(ei, k3, q3, v3, acc3);
    // Pool + classifier
    k_pool<<<gNode, TB, 0, stream>>>(acc3, batch, K, L);
    k_final<<<gFin, TB, 0, stream>>>(K, L, lin_W, lin_b, out);
}

// Round 2
// 512.427 us; speedup vs baseline: 4.5300x; 4.5300x over previous
//
#include <hip/hip_runtime.h>

#define N_NODES 100000
#define N_EDGES 1600000
#define N_GRAPH 1024

__device__ __forceinline__ float sigm(float z) { return 1.0f / (1.0f + __expf(-z)); }

// ======================= CSR build =======================
__global__ __launch_bounds__(256) void k_hist(const int* __restrict__ ei,
                                              int* __restrict__ cnt)
{
    int e = blockIdx.x * 256 + threadIdx.x;
    if (e >= N_EDGES) return;
    atomicAdd(&cnt[ei[N_EDGES + e]], 1);
}

// block-level inclusive scan (1024 elems/block) -> exclusive partial + block sums
__global__ __launch_bounds__(1024) void k_scan1(const int* __restrict__ cnt,
                                                int* __restrict__ excl,
                                                int* __restrict__ bsum)
{
    __shared__ int s[1024];
    int t = threadIdx.x;
    int gid = blockIdx.x * 1024 + t;
    int v = (gid < N_NODES) ? cnt[gid] : 0;
    s[t] = v;
    __syncthreads();
#pragma unroll
    for (int off = 1; off < 1024; off <<= 1) {
        int u = (t >= off) ? s[t - off] : 0;
        __syncthreads();
        s[t] += u;
        __syncthreads();
    }
    if (gid < N_NODES) excl[gid] = s[t] - v;
    if (t == 1023) bsum[blockIdx.x] = s[t];
}

#define NBLK1 98  // ceil(100000/1024)
__global__ __launch_bounds__(128) void k_scan2(const int* __restrict__ bsum,
                                               int* __restrict__ boff)
{
    __shared__ int s[128];
    int t = threadIdx.x;
    int v = (t < NBLK1) ? bsum[t] : 0;
    s[t] = v;
    __syncthreads();
#pragma unroll
    for (int off = 1; off < 128; off <<= 1) {
        int u = (t >= off) ? s[t - off] : 0;
        __syncthreads();
        s[t] += u;
        __syncthreads();
    }
    boff[t] = s[t] - v;  // exclusive
}

__global__ __launch_bounds__(256) void k_scan3(const int* __restrict__ excl,
                                               const int* __restrict__ boff,
                                               int* __restrict__ starts,
                                               int* __restrict__ cursor)
{
    int i = blockIdx.x * 256 + threadIdx.x;
    if (i >= N_NODES) return;
    int v = excl[i] + boff[i >> 10];
    starts[i] = v;
    cursor[i] = v;
}

__global__ __launch_bounds__(256) void k_scatter(const int* __restrict__ ei,
                                                 int* __restrict__ cursor,
                                                 int* __restrict__ csr_src)
{
    int e = blockIdx.x * 256 + threadIdx.x;
    if (e >= N_EDGES) return;
    int d = ei[N_EDGES + e];
    int pos = atomicAdd(&cursor[d], 1);
    csr_src[pos] = ei[e];
}

// ======================= Layer 1: ResGated(1 -> 32), fused gather =======================
// h1[i] = sum_{s->i} sigm(k_i + q_s) * v_s  +  x_i*Wskip + b   (all rank-1 in x)
__global__ __launch_bounds__(256) void k_gath1(
    const float* __restrict__ x, const int* __restrict__ csr_src,
    const int* __restrict__ starts, const int* __restrict__ cnt,
    const float* __restrict__ Wk, const float* __restrict__ bk,
    const float* __restrict__ Wq, const float* __restrict__ bq,
    const float* __restrict__ Wv, const float* __restrict__ bv,
    const float* __restrict__ Wskip, const float* __restrict__ b,
    float* __restrict__ h1)
{
    int tid = blockIdx.x * 256 + threadIdx.x;
    if (tid >= N_NODES * 8) return;
    int i = tid >> 3, l = tid & 7;

    float xd = x[i];
    float4 wk = ((const float4*)Wk)[l], bk4 = ((const float4*)bk)[l];
    float4 wq = ((const float4*)Wq)[l], bq4 = ((const float4*)bq)[l];
    float4 wv = ((const float4*)Wv)[l], bv4 = ((const float4*)bv)[l];
    float4 kk = make_float4(fmaf(xd, wk.x, bk4.x), fmaf(xd, wk.y, bk4.y),
                            fmaf(xd, wk.z, bk4.z), fmaf(xd, wk.w, bk4.w));

    int base = starts[i], deg = cnt[i];
    float4 a0 = make_float4(0.f, 0.f, 0.f, 0.f);
    float4 a1 = make_float4(0.f, 0.f, 0.f, 0.f);
    int e = 0;
    for (; e + 1 < deg; e += 2) {
        int s0 = csr_src[base + e];
        int s1 = csr_src[base + e + 1];
        float x0 = x[s0], x1 = x[s1];
        a0.x += sigm(kk.x + fmaf(x0, wq.x, bq4.x)) * fmaf(x0, wv.x, bv4.x);
        a0.y += sigm(kk.y + fmaf(x0, wq.y, bq4.y)) * fmaf(x0, wv.y, bv4.y);
        a0.z += sigm(kk.z + fmaf(x0, wq.z, bq4.z)) * fmaf(x0, wv.z, bv4.z);
        a0.w += sigm(kk.w + fmaf(x0, wq.w, bq4.w)) * fmaf(x0, wv.w, bv4.w);
        a1.x += sigm(kk.x + fmaf(x1, wq.x, bq4.x)) * fmaf(x1, wv.x, bv4.x);
        a1.y += sigm(kk.y + fmaf(x1, wq.y, bq4.y)) * fmaf(x1, wv.y, bv4.y);
        a1.z += sigm(kk.z + fmaf(x1, wq.z, bq4.z)) * fmaf(x1, wv.z, bv4.z);
        a1.w += sigm(kk.w + fmaf(x1, wq.w, bq4.w)) * fmaf(x1, wv.w, bv4.w);
    }
    if (e < deg) {
        int s0 = csr_src[base + e];
        float x0 = x[s0];
        a0.x += sigm(kk.x + fmaf(x0, wq.x, bq4.x)) * fmaf(x0, wv.x, bv4.x);
        a0.y += sigm(kk.y + fmaf(x0, wq.y, bq4.y)) * fmaf(x0, wv.y, bv4.y);
        a0.z += sigm(kk.z + fmaf(x0, wq.z, bq4.z)) * fmaf(x0, wv.z, bv4.z);
        a0.w += sigm(kk.w + fmaf(x0, wq.w, bq4.w)) * fmaf(x0, wv.w, bv4.w);
    }
    float4 ws4 = ((const float4*)Wskip)[l];
    float4 bb4 = ((const float4*)b)[l];
    float4 o = make_float4(a0.x + a1.x + fmaf(xd, ws4.x, bb4.x),
                           a0.y + a1.y + fmaf(xd, ws4.y, bb4.y),
                           a0.z + a1.z + fmaf(xd, ws4.z, bb4.z),
                           a0.w + a1.w + fmaf(xd, ws4.w, bb4.w));
    ((float4*)(h1 + (size_t)i * 32))[l] = o;
}

// dot of h[32] against 4 consecutive LDS weight columns (stride = fout)
__device__ __forceinline__ float4 dot4(const float* __restrict__ h,
                                       const float* __restrict__ Wcol, int stride)
{
    float4 a = make_float4(0.f, 0.f, 0.f, 0.f);
#pragma unroll
    for (int k = 0; k < 32; k++) {
        float4 w = *(const float4*)(Wcol + k * stride);
        float hk = h[k];
        a.x = fmaf(hk, w.x, a.x);
        a.y = fmaf(hk, w.y, a.y);
        a.z = fmaf(hk, w.z, a.z);
        a.w = fmaf(hk, w.w, a.w);
    }
    return a;
}

// ======================= Layer 2: FiLM node-side =======================
__global__ __launch_bounds__(256) void k_node2(
    const float* __restrict__ h1,
    const float* __restrict__ Wlin, const float* __restrict__ Wfilm,
    const float* __restrict__ bfilm, const float* __restrict__ Wls,
    const float* __restrict__ Wfs,
    float* __restrict__ skip2, float* __restrict__ bg2, float* __restrict__ xl)
{
    __shared__ float sWlin[32 * 32], sWfilm[32 * 64], sWls[32 * 32], sWfs[32 * 64];
    int t = threadIdx.x;
    for (int idx = t; idx < 1024; idx += 256) sWlin[idx] = Wlin[idx];
    for (int idx = t; idx < 2048; idx += 256) sWfilm[idx] = Wfilm[idx];
    for (int idx = t; idx < 1024; idx += 256) sWls[idx] = Wls[idx];
    for (int idx = t; idx < 2048; idx += 256) sWfs[idx] = Wfs[idx];
    __syncthreads();

    int tid = blockIdx.x * 256 + t;
    if (tid >= N_NODES * 8) return;
    int i = tid >> 3, l = tid & 7;

    float h[32];
    const float4* hp = (const float4*)(h1 + (size_t)i * 32);
#pragma unroll
    for (int j = 0; j < 8; j++) {
        float4 v = hp[j];
        h[4 * j + 0] = fmaxf(v.x, 0.f);
        h[4 * j + 1] = fmaxf(v.y, 0.f);
        h[4 * j + 2] = fmaxf(v.z, 0.f);
        h[4 * j + 3] = fmaxf(v.w, 0.f);
    }

    float4 bs = dot4(h, sWfs + l * 4, 64);
    float4 gs = dot4(h, sWfs + 32 + l * 4, 64);
    float4 ls = dot4(h, sWls + l * 4, 32);
    float4 sk = make_float4(fmaxf(fmaf(gs.x, ls.x, bs.x), 0.f),
                            fmaxf(fmaf(gs.y, ls.y, bs.y), 0.f),
                            fmaxf(fmaf(gs.z, ls.z, bs.z), 0.f),
                            fmaxf(fmaf(gs.w, ls.w, bs.w), 0.f));
    ((float4*)(skip2 + (size_t)i * 32))[l] = sk;

    float4 bf0 = ((const float4*)bfilm)[l * 2];
    float4 bf1 = ((const float4*)bfilm)[l * 2 + 1];
    float4 f0 = dot4(h, sWfilm + l * 8, 64);
    float4 f1 = dot4(h, sWfilm + l * 8 + 4, 64);
    f0.x += bf0.x; f0.y += bf0.y; f0.z += bf0.z; f0.w += bf0.w;
    f1.x += bf1.x; f1.y += bf1.y; f1.z += bf1.z; f1.w += bf1.w;
    float4* bgp = (float4*)(bg2 + (size_t)i * 64);
    bgp[l * 2] = f0;
    bgp[l * 2 + 1] = f1;

    float4 xo = dot4(h, sWlin + l * 4, 32);
    ((float4*)(xl + (size_t)i * 32))[l] = xo;
}

// FiLM gather: h2 = relu(skip2 + mean_{s->i} relu(gamma_i*xl_s + beta_i))
__global__ __launch_bounds__(256) void k_gath2(
    const int* __restrict__ csr_src, const int* __restrict__ starts,
    const int* __restrict__ cnt,
    const float* __restrict__ bg2, const float* __restrict__ xl,
    const float* __restrict__ skip2, float* __restrict__ h2)
{
    int tid = blockIdx.x * 256 + threadIdx.x;
    if (tid >= N_NODES * 8) return;
    int i = tid >> 3, l = tid & 7;

    float4 be = ((const float4*)(bg2 + (size_t)i * 64))[l];
    float4 ga = ((const float4*)(bg2 + (size_t)i * 64 + 32))[l];

    int base = starts[i], deg = cnt[i];
    float4 a0 = make_float4(0.f, 0.f, 0.f, 0.f);
    float4 a1 = make_float4(0.f, 0.f, 0.f, 0.f);
    int e = 0;
    for (; e + 1 < deg; e += 2) {
        int s0 = csr_src[base + e];
        int s1 = csr_src[base + e + 1];
        float4 u = ((const float4*)(xl + (size_t)s0 * 32))[l];
        float4 w = ((const float4*)(xl + (size_t)s1 * 32))[l];
        a0.x += fmaxf(fmaf(ga.x, u.x, be.x), 0.f);
        a0.y += fmaxf(fmaf(ga.y, u.y, be.y), 0.f);
        a0.z += fmaxf(fmaf(ga.z, u.z, be.z), 0.f);
        a0.w += fmaxf(fmaf(ga.w, u.w, be.w), 0.f);
        a1.x += fmaxf(fmaf(ga.x, w.x, be.x), 0.f);
        a1.y += fmaxf(fmaf(ga.y, w.y, be.y), 0.f);
        a1.z += fmaxf(fmaf(ga.z, w.z, be.z), 0.f);
        a1.w += fmaxf(fmaf(ga.w, w.w, be.w), 0.f);
    }
    if (e < deg) {
        int s0 = csr_src[base + e];
        float4 u = ((const float4*)(xl + (size_t)s0 * 32))[l];
        a0.x += fmaxf(fmaf(ga.x, u.x, be.x), 0.f);
        a0.y += fmaxf(fmaf(ga.y, u.y, be.y), 0.f);
        a0.z += fmaxf(fmaf(ga.z, u.z, be.z), 0.f);
        a0.w += fmaxf(fmaf(ga.w, u.w, be.w), 0.f);
    }
    float inv = 1.0f / fmaxf((float)deg, 1.0f);
    float4 sk = ((const float4*)(skip2 + (size_t)i * 32))[l];
    float4 o = make_float4(fmaxf(fmaf(a0.x + a1.x, inv, sk.x), 0.f),
                           fmaxf(fmaf(a0.y + a1.y, inv, sk.y), 0.f),
                           fmaxf(fmaf(a0.z + a1.z, inv, sk.z), 0.f),
                           fmaxf(fmaf(a0.w + a1.w, inv, sk.w), 0.f));
    ((float4*)(h2 + (size_t)i * 32))[l] = o;
}

// ======================= Layer 3 node-side =======================
__global__ __launch_bounds__(256) void k_node3(
    const float* __restrict__ h2,
    const float* __restrict__ Wk, const float* __restrict__ bk,
    const float* __restrict__ Wq, const float* __restrict__ bq,
    const float* __restrict__ Wv, const float* __restrict__ bv,
    const float* __restrict__ Wskip, const float* __restrict__ b,
    float* __restrict__ k3, float* __restrict__ q3, float* __restrict__ v3,
    float* __restrict__ acc3)
{
    __shared__ float sWk[1024], sWq[1024], sWv[1024], sWs[1024];
    int t = threadIdx.x;
    for (int idx = t; idx < 1024; idx += 256) {
        sWk[idx] = Wk[idx];
        sWq[idx] = Wq[idx];
        sWv[idx] = Wv[idx];
        sWs[idx] = Wskip[idx];
    }
    __syncthreads();

    int tid = blockIdx.x * 256 + t;
    if (tid >= N_NODES * 8) return;
    int i = tid >> 3, l = tid & 7;

    float h[32];
    const float4* hp = (const float4*)(h2 + (size_t)i * 32);
#pragma unroll
    for (int j = 0; j < 8; j++) {
        float4 v = hp[j];
        h[4 * j + 0] = v.x; h[4 * j + 1] = v.y;
        h[4 * j + 2] = v.z; h[4 * j + 3] = v.w;
    }

    float4 bk4 = ((const float4*)bk)[l];
    float4 bq4 = ((const float4*)bq)[l];
    float4 bv4 = ((const float4*)bv)[l];
    float4 bb4 = ((const float4*)b)[l];

    float4 kk = dot4(h, sWk + l * 4, 32);
    kk.x += bk4.x; kk.y += bk4.y; kk.z += bk4.z; kk.w += bk4.w;
    ((float4*)(k3 + (size_t)i * 32))[l] = kk;

    float4 qq = dot4(h, sWq + l * 4, 32);
    qq.x += bq4.x; qq.y += bq4.y; qq.z += bq4.z; qq.w += bq4.w;
    ((float4*)(q3 + (size_t)i * 32))[l] = qq;

    float4 vv = dot4(h, sWv + l * 4, 32);
    vv.x += bv4.x; vv.y += bv4.y; vv.z += bv4.z; vv.w += bv4.w;
    ((float4*)(v3 + (size_t)i * 32))[l] = vv;

    float4 ss = dot4(h, sWs + l * 4, 32);
    ss.x += bb4.x; ss.y += bb4.y; ss.z += bb4.z; ss.w += bb4.w;
    ((float4*)(acc3 + (size_t)i * 32))[l] = ss;
}

// ResGated gather: h3 = acc3_init + sum_{s->i} sigm(k3_i + q3_s) * v3_s  (in place on acc3)
__global__ __launch_bounds__(256) void k_gath3(
    const int* __restrict__ csr_src, const int* __restrict__ starts,
    const int* __restrict__ cnt,
    const float* __restrict__ k3, const float* __restrict__ q3,
    const float* __restrict__ v3, float* __restrict__ acc3)
{
    int tid = blockIdx.x * 256 + threadIdx.x;
    if (tid >= N_NODES * 8) return;
    int i = tid >> 3, l = tid & 7;

    float4 kk = ((const float4*)(k3 + (size_t)i * 32))[l];
    int base = starts[i], deg = cnt[i];
    float4 a0 = make_float4(0.f, 0.f, 0.f, 0.f);
    float4 a1 = make_float4(0.f, 0.f, 0.f, 0.f);
    int e = 0;
    for (; e + 1 < deg; e += 2) {
        int s0 = csr_src[base + e];
        int s1 = csr_src[base + e + 1];
        float4 q0 = ((const float4*)(q3 + (size_t)s0 * 32))[l];
        float4 v0 = ((const float4*)(v3 + (size_t)s0 * 32))[l];
        float4 q1 = ((const float4*)(q3 + (size_t)s1 * 32))[l];
        float4 v1 = ((const float4*)(v3 + (size_t)s1 * 32))[l];
        a0.x += sigm(kk.x + q0.x) * v0.x;
        a0.y += sigm(kk.y + q0.y) * v0.y;
        a0.z += sigm(kk.z + q0.z) * v0.z;
        a0.w += sigm(kk.w + q0.w) * v0.w;
        a1.x += sigm(kk.x + q1.x) * v1.x;
        a1.y += sigm(kk.y + q1.y) * v1.y;
        a1.z += sigm(kk.z + q1.z) * v1.z;
        a1.w += sigm(kk.w + q1.w) * v1.w;
    }
    if (e < deg) {
        int s0 = csr_src[base + e];
        float4 q0 = ((const float4*)(q3 + (size_t)s0 * 32))[l];
        float4 v0 = ((const float4*)(v3 + (size_t)s0 * 32))[l];
        a0.x += sigm(kk.x + q0.x) * v0.x;
        a0.y += sigm(kk.y + q0.y) * v0.y;
        a0.z += sigm(kk.z + q0.z) * v0.z;
        a0.w += sigm(kk.w + q0.w) * v0.w;
    }
    float4* op = (float4*)(acc3 + (size_t)i * 32) + l;
    float4 cur = *op;
    cur.x += a0.x + a1.x;
    cur.y += a0.y + a1.y;
    cur.z += a0.z + a1.z;
    cur.w += a0.w + a1.w;
    *op = cur;
}

// ======================= pool (batch is sorted -> segment ranges) =======================
__global__ __launch_bounds__(256) void k_gstart(const int* __restrict__ batch,
                                                int* __restrict__ gstart)
{
    int g = blockIdx.x * 256 + threadIdx.x;
    if (g > N_GRAPH) return;
    int lo = 0, hi = N_NODES;
    while (lo < hi) {
        int mid = (lo + hi) >> 1;
        if (batch[mid] < g) lo = mid + 1; else hi = mid;
    }
    gstart[g] = lo;
}

// one wave per graph: 8 node-subgroups x 8 feature-groups, shfl reduce
__global__ __launch_bounds__(256) void k_pool(
    const float* __restrict__ h3, const int* __restrict__ gstart,
    float* __restrict__ gmean)
{
    int tid = blockIdx.x * 256 + threadIdx.x;
    int g = tid >> 6;
    if (g >= N_GRAPH) return;
    int lane = tid & 63;
    int sub = lane >> 3, fg = lane & 7;
    int gs = gstart[g], ge = gstart[g + 1];

    float4 a = make_float4(0.f, 0.f, 0.f, 0.f);
    for (int j = gs + sub; j < ge; j += 8) {
        float4 v = ((const float4*)(h3 + (size_t)j * 32))[fg];
        a.x += v.x; a.y += v.y; a.z += v.z; a.w += v.w;
    }
#pragma unroll
    for (int off = 8; off < 64; off <<= 1) {
        a.x += __shfl_xor(a.x, off);
        a.y += __shfl_xor(a.y, off);
        a.z += __shfl_xor(a.z, off);
        a.w += __shfl_xor(a.w, off);
    }
    if (sub == 0) {
        float inv = 1.0f / fmaxf((float)(ge - gs), 1.0f);
        a.x *= inv; a.y *= inv; a.z *= inv; a.w *= inv;
        ((float4*)(gmean + (size_t)g * 32))[fg] = a;
    }
}

__global__ __launch_bounds__(256) void k_final(
    const float* __restrict__ gmean,
    const float* __restrict__ linW, const float* __restrict__ linb,
    float* __restrict__ out)
{
    int tid = blockIdx.x * 256 + threadIdx.x;
    if (tid >= N_GRAPH * 10) return;
    int g = tid / 10, c = tid % 10;
    const float* gr = gmean + (size_t)g * 32;
    float a = 0.f;
#pragma unroll
    for (int k = 0; k < 32; k++) a = fmaf(gr[k], linW[k * 10 + c], a);
    out[tid] = a + linb[c];
}

extern "C" void kernel_launch(void* const* d_in, const int* in_sizes, int n_in,
                              void* d_out, int out_size, void* d_ws, size_t ws_size,
                              hipStream_t stream)
{
    const float* x      = (const float*)d_in[0];
    const int*   ei     = (const int*)d_in[1];
    const int*   batch  = (const int*)d_in[2];
    const float* c1_Wk   = (const float*)d_in[4];
    const float* c1_bk   = (const float*)d_in[5];
    const float* c1_Wq   = (const float*)d_in[6];
    const float* c1_bq   = (const float*)d_in[7];
    const float* c1_Wv   = (const float*)d_in[8];
    const float* c1_bv   = (const float*)d_in[9];
    const float* c1_Wsk  = (const float*)d_in[10];
    const float* c1_b    = (const float*)d_in[11];
    const float* c2_Wlin = (const float*)d_in[12];
    const float* c2_Wfilm= (const float*)d_in[13];
    const float* c2_bfilm= (const float*)d_in[14];
    const float* c2_Wls  = (const float*)d_in[15];
    const float* c2_Wfs  = (const float*)d_in[16];
    const float* c3_Wk   = (const float*)d_in[17];
    const float* c3_bk   = (const float*)d_in[18];
    const float* c3_Wq   = (const float*)d_in[19];
    const float* c3_bq   = (const float*)d_in[20];
    const float* c3_Wv   = (const float*)d_in[21];
    const float* c3_bv   = (const float*)d_in[22];
    const float* c3_Wsk  = (const float*)d_in[23];
    const float* c3_b    = (const float*)d_in[24];
    const float* lin_W   = (const float*)d_in[25];
    const float* lin_b   = (const float*)d_in[26];
    float* out = (float*)d_out;

    const size_t N = N_NODES;

    // ---- workspace layout (ints first, then 16B-aligned float region) ----
    int* icnt    = (int*)d_ws;            // N
    int* iexcl   = icnt + N;              // N
    int* istarts = iexcl + N;             // N (also final cursor after scan3? no: separate)
    int* icur    = istarts + N;           // N
    int* ibsum   = icur + N;              // 128
    int* iboff   = ibsum + 128;           // 128
    int* igstart = iboff + 128;           // 1025 (+pad to 1056)
    int* icsr    = igstart + 1056;        // E
    float* h1    = (float*)(icsr + N_EDGES);  // N*32  (reused as h2)
    float* skip2 = h1 + N * 32;               // N*32  (reused as k3)
    float* xl    = skip2 + N * 32;            // N*32  (reused as q3)
    float* bg2   = xl + N * 32;               // N*64  (reused as v3 | acc3/h3)
    float* gmean = bg2 + N * 64;              // G*32

    hipMemsetAsync(icnt, 0, N * sizeof(int), stream);

    const int TB = 256;
    int gEdgeT = (N_EDGES + TB - 1) / TB;       // 6250
    int gNodeT = ((int)N + TB - 1) / TB;        // 391
    int gNode8 = (N_NODES * 8 + TB - 1) / TB;   // 3125
    int gFin   = (N_GRAPH * 10 + TB - 1) / TB;  // 40

    // CSR build
    k_hist<<<gEdgeT, TB, 0, stream>>>(ei, icnt);
    k_scan1<<<NBLK1, 1024, 0, stream>>>(icnt, iexcl, ibsum);
    k_scan2<<<1, 128, 0, stream>>>(ibsum, iboff);
    k_scan3<<<gNodeT, TB, 0, stream>>>(iexcl, iboff, istarts, icur);
    k_scatter<<<gEdgeT, TB, 0, stream>>>(ei, icur, icsr);
    k_gstart<<<5, TB, 0, stream>>>(batch, igstart);

    // Layer 1 (fused gather, no atomics)
    k_gath1<<<gNode8, TB, 0, stream>>>(x, icsr, istarts, icnt,
                                       c1_Wk, c1_bk, c1_Wq, c1_bq,
                                       c1_Wv, c1_bv, c1_Wsk, c1_b, h1);
    // Layer 2 (FiLM)
    k_node2<<<gNode8, TB, 0, stream>>>(h1, c2_Wlin, c2_Wfilm, c2_bfilm,
                                       c2_Wls, c2_Wfs, skip2, bg2, xl);
    float* h2 = h1;  // reuse
    k_gath2<<<gNode8, TB, 0, stream>>>(icsr, istarts, icnt, bg2, xl, skip2, h2);
    // Layer 3 (ResGated)
    float* k3 = skip2;
    float* q3 = xl;
    float* v3 = bg2;
    float* acc3 = bg2 + N * 32;
    k_node3<<<gNode8, TB, 0, stream>>>(h2, c3_Wk, c3_bk, c3_Wq, c3_bq,
                                       c3_Wv, c3_bv, c3_Wsk, c3_b,
                                       k3, q3, v3, acc3);
    k_gath3<<<gNode8, TB, 0, stream>>>(icsr, istarts, icnt, k3, q3, v3, acc3);
    // Pool + classifier
    k_pool<<<256, TB, 0, stream>>>(acc3, igstart, gmean);
    k_final<<<gFin, TB, 0, stream>>>(gmean, lin_W, lin_b, out);
}

// Round 4
// 338.366 us; speedup vs baseline: 6.8603x; 1.5144x over previous
//
#include <hip/hip_runtime.h>

#define N_NODES 100000
#define N_EDGES 1600000
#define N_GRAPH 1024
#define NB      196      // buckets of 512 nodes: ceil(100000/512)
#define BCAP    10240    // bucket capacity (mean 8192, sigma ~90 -> 22 sigma slack)
#define PEPT    16       // edges per thread in partition

typedef unsigned short u16;
typedef unsigned int   u32;

__device__ __forceinline__ float sigm(float z) { return 1.0f / (1.0f + __expf(-z)); }
__device__ __forceinline__ u16 f2bf(float f) {
    u32 u = __float_as_uint(f);
    u += 0x7FFFu + ((u >> 16) & 1u);
    return (u16)(u >> 16);
}
__device__ __forceinline__ float bf2f(u16 h) { return __uint_as_float(((u32)h) << 16); }

// ======================= CSR build: bucket partition =======================
// pack: (dst&511)<<17 | src   (src < 2^17, local dst < 2^9 -> 26 bits)
__global__ __launch_bounds__(256) void k_partition(const int* __restrict__ ei,
                                                   int* __restrict__ gcnt,
                                                   int* __restrict__ bucketed)
{
    __shared__ int lcnt[NB], gbase[NB], lcur[NB];
    int t = threadIdx.x;
    for (int i = t; i < NB; i += 256) { lcnt[i] = 0; lcur[i] = 0; }
    __syncthreads();

    int ebase = blockIdx.x * (256 * PEPT);
    int pk[PEPT], bk[PEPT];
#pragma unroll
    for (int r = 0; r < PEPT; r++) {
        int e = ebase + r * 256 + t;
        if (e < N_EDGES) {
            int d = ei[N_EDGES + e];
            int s = ei[e];
            int b = d >> 9;
            bk[r] = b;
            pk[r] = ((d & 511) << 17) | s;
            atomicAdd(&lcnt[b], 1);
        } else bk[r] = -1;
    }
    __syncthreads();
    for (int i = t; i < NB; i += 256) gbase[i] = atomicAdd(&gcnt[i], lcnt[i]);
    __syncthreads();
#pragma unroll
    for (int r = 0; r < PEPT; r++) {
        if (bk[r] >= 0) {
            int b = bk[r];
            int pos = gbase[b] + atomicAdd(&lcur[b], 1);
            bucketed[b * BCAP + pos] = pk[r];
        }
    }
}

// exclusive scan of 196 bucket counts (1 block)
__global__ __launch_bounds__(256) void k_bscan(const int* __restrict__ gcnt,
                                               int* __restrict__ base)
{
    __shared__ int s[256];
    int t = threadIdx.x;
    int v = (t < NB) ? gcnt[t] : 0;
    s[t] = v;
    __syncthreads();
#pragma unroll
    for (int off = 1; off < 256; off <<= 1) {
        int u = (t >= off) ? s[t - off] : 0;
        __syncthreads();
        s[t] += u;
        __syncthreads();
    }
    base[t] = s[t] - v;
}

// one block per bucket: local CSR (count/scan/place) in LDS, contiguous global writes
__global__ __launch_bounds__(512) void k_place(const int* __restrict__ bucketed,
                                               const int* __restrict__ gcnt,
                                               const int* __restrict__ base,
                                               int* __restrict__ csr,
                                               int* __restrict__ starts,
                                               int* __restrict__ cnt)
{
    __shared__ int scnt[512], sexc[512], scur[512];
    int b = blockIdx.x, t = threadIdx.x;
    int ecnt = gcnt[b];
    int ebase = base[b];
    const int* bp = bucketed + b * BCAP;

    scnt[t] = 0; scur[t] = 0;
    __syncthreads();
    for (int e = t; e < ecnt; e += 512) atomicAdd(&scnt[bp[e] >> 17], 1);
    __syncthreads();
    int v = scnt[t];
    sexc[t] = v;
    __syncthreads();
#pragma unroll
    for (int off = 1; off < 512; off <<= 1) {
        int u = (t >= off) ? sexc[t - off] : 0;
        __syncthreads();
        sexc[t] += u;
        __syncthreads();
    }
    int excl = sexc[t] - v;
    __syncthreads();
    sexc[t] = excl;
    __syncthreads();

    int node = b * 512 + t;
    if (node < N_NODES) { starts[node] = ebase + excl; cnt[node] = v; }

    for (int e = t; e < ecnt; e += 512) {
        int p = bp[e];
        int ld = p >> 17;
        int pos = ebase + sexc[ld] + atomicAdd(&scur[ld], 1);
        csr[pos] = p & 0x1FFFF;
    }
}

// ======================= Layer 1: ResGated(1 -> 32), fused gather =======================
__global__ __launch_bounds__(256) void k_gath1(
    const float* __restrict__ x, const int* __restrict__ csr_src,
    const int* __restrict__ starts, const int* __restrict__ cnt,
    const float* __restrict__ Wk, const float* __restrict__ bk,
    const float* __restrict__ Wq, const float* __restrict__ bq,
    const float* __restrict__ Wv, const float* __restrict__ bv,
    const float* __restrict__ Wskip, const float* __restrict__ b,
    float* __restrict__ h1)
{
    int tid = blockIdx.x * 256 + threadIdx.x;
    if (tid >= N_NODES * 8) return;
    int i = tid >> 3, l = tid & 7;

    float xd = x[i];
    float4 wk = ((const float4*)Wk)[l], bk4 = ((const float4*)bk)[l];
    float4 wq = ((const float4*)Wq)[l], bq4 = ((const float4*)bq)[l];
    float4 wv = ((const float4*)Wv)[l], bv4 = ((const float4*)bv)[l];
    float4 kk = make_float4(fmaf(xd, wk.x, bk4.x), fmaf(xd, wk.y, bk4.y),
                            fmaf(xd, wk.z, bk4.z), fmaf(xd, wk.w, bk4.w));

    int base = starts[i], deg = cnt[i];
    float4 a0 = make_float4(0.f, 0.f, 0.f, 0.f);
    float4 a1 = make_float4(0.f, 0.f, 0.f, 0.f);
    int e = 0;
    for (; e + 1 < deg; e += 2) {
        int s0 = csr_src[base + e];
        int s1 = csr_src[base + e + 1];
        float x0 = x[s0], x1 = x[s1];
        a0.x += sigm(kk.x + fmaf(x0, wq.x, bq4.x)) * fmaf(x0, wv.x, bv4.x);
        a0.y += sigm(kk.y + fmaf(x0, wq.y, bq4.y)) * fmaf(x0, wv.y, bv4.y);
        a0.z += sigm(kk.z + fmaf(x0, wq.z, bq4.z)) * fmaf(x0, wv.z, bv4.z);
        a0.w += sigm(kk.w + fmaf(x0, wq.w, bq4.w)) * fmaf(x0, wv.w, bv4.w);
        a1.x += sigm(kk.x + fmaf(x1, wq.x, bq4.x)) * fmaf(x1, wv.x, bv4.x);
        a1.y += sigm(kk.y + fmaf(x1, wq.y, bq4.y)) * fmaf(x1, wv.y, bv4.y);
        a1.z += sigm(kk.z + fmaf(x1, wq.z, bq4.z)) * fmaf(x1, wv.z, bv4.z);
        a1.w += sigm(kk.w + fmaf(x1, wq.w, bq4.w)) * fmaf(x1, wv.w, bv4.w);
    }
    if (e < deg) {
        int s0 = csr_src[base + e];
        float x0 = x[s0];
        a0.x += sigm(kk.x + fmaf(x0, wq.x, bq4.x)) * fmaf(x0, wv.x, bv4.x);
        a0.y += sigm(kk.y + fmaf(x0, wq.y, bq4.y)) * fmaf(x0, wv.y, bv4.y);
        a0.z += sigm(kk.z + fmaf(x0, wq.z, bq4.z)) * fmaf(x0, wv.z, bv4.z);
        a0.w += sigm(kk.w + fmaf(x0, wq.w, bq4.w)) * fmaf(x0, wv.w, bv4.w);
    }
    float4 ws4 = ((const float4*)Wskip)[l];
    float4 bb4 = ((const float4*)b)[l];
    float4 o = make_float4(a0.x + a1.x + fmaf(xd, ws4.x, bb4.x),
                           a0.y + a1.y + fmaf(xd, ws4.y, bb4.y),
                           a0.z + a1.z + fmaf(xd, ws4.z, bb4.z),
                           a0.w + a1.w + fmaf(xd, ws4.w, bb4.w));
    ((float4*)(h1 + (size_t)i * 32))[l] = o;
}

__device__ __forceinline__ float4 dot4(const float* __restrict__ h,
                                       const float* __restrict__ Wcol, int stride)
{
    float4 a = make_float4(0.f, 0.f, 0.f, 0.f);
#pragma unroll
    for (int k = 0; k < 32; k++) {
        float4 w = *(const float4*)(Wcol + k * stride);
        float hk = h[k];
        a.x = fmaf(hk, w.x, a.x);
        a.y = fmaf(hk, w.y, a.y);
        a.z = fmaf(hk, w.z, a.z);
        a.w = fmaf(hk, w.w, a.w);
    }
    return a;
}

// ======================= Layer 2: FiLM node-side (xl stored bf16) =======================
__global__ __launch_bounds__(256) void k_node2(
    const float* __restrict__ h1,
    const float* __restrict__ Wlin, const float* __restrict__ Wfilm,
    const float* __restrict__ bfilm, const float* __restrict__ Wls,
    const float* __restrict__ Wfs,
    float* __restrict__ skip2, float* __restrict__ bg2, u16* __restrict__ xlb)
{
    __shared__ float sWlin[32 * 32], sWfilm[32 * 64], sWls[32 * 32], sWfs[32 * 64];
    int t = threadIdx.x;
    for (int idx = t; idx < 1024; idx += 256) sWlin[idx] = Wlin[idx];
    for (int idx = t; idx < 2048; idx += 256) sWfilm[idx] = Wfilm[idx];
    for (int idx = t; idx < 1024; idx += 256) sWls[idx] = Wls[idx];
    for (int idx = t; idx < 2048; idx += 256) sWfs[idx] = Wfs[idx];
    __syncthreads();

    int tid = blockIdx.x * 256 + t;
    if (tid >= N_NODES * 8) return;
    int i = tid >> 3, l = tid & 7;

    float h[32];
    const float4* hp = (const float4*)(h1 + (size_t)i * 32);
#pragma unroll
    for (int j = 0; j < 8; j++) {
        float4 v = hp[j];
        h[4 * j + 0] = fmaxf(v.x, 0.f);
        h[4 * j + 1] = fmaxf(v.y, 0.f);
        h[4 * j + 2] = fmaxf(v.z, 0.f);
        h[4 * j + 3] = fmaxf(v.w, 0.f);
    }

    float4 bs = dot4(h, sWfs + l * 4, 64);
    float4 gs = dot4(h, sWfs + 32 + l * 4, 64);
    float4 ls = dot4(h, sWls + l * 4, 32);
    float4 sk = make_float4(fmaxf(fmaf(gs.x, ls.x, bs.x), 0.f),
                            fmaxf(fmaf(gs.y, ls.y, bs.y), 0.f),
                            fmaxf(fmaf(gs.z, ls.z, bs.z), 0.f),
                            fmaxf(fmaf(gs.w, ls.w, bs.w), 0.f));
    ((float4*)(skip2 + (size_t)i * 32))[l] = sk;

    float4 bf0 = ((const float4*)bfilm)[l * 2];
    float4 bf1 = ((const float4*)bfilm)[l * 2 + 1];
    float4 f0 = dot4(h, sWfilm + l * 8, 64);
    float4 f1 = dot4(h, sWfilm + l * 8 + 4, 64);
    f0.x += bf0.x; f0.y += bf0.y; f0.z += bf0.z; f0.w += bf0.w;
    f1.x += bf1.x; f1.y += bf1.y; f1.z += bf1.z; f1.w += bf1.w;
    float4* bgp = (float4*)(bg2 + (size_t)i * 64);
    bgp[l * 2] = f0;
    bgp[l * 2 + 1] = f1;

    float4 xo = dot4(h, sWlin + l * 4, 32);
    ushort4 xp;
    xp.x = f2bf(xo.x); xp.y = f2bf(xo.y); xp.z = f2bf(xo.z); xp.w = f2bf(xo.w);
    ((ushort4*)xlb)[(size_t)i * 8 + l] = xp;
}

// FiLM gather: h2 = relu(skip2 + mean relu(gamma_i*xl_s + beta_i)), xl in bf16
__global__ __launch_bounds__(256) void k_gath2(
    const int* __restrict__ csr_src, const int* __restrict__ starts,
    const int* __restrict__ cnt,
    const float* __restrict__ bg2, const u16* __restrict__ xlb,
    const float* __restrict__ skip2, float* __restrict__ h2)
{
    int tid = blockIdx.x * 256 + threadIdx.x;
    if (tid >= N_NODES * 8) return;
    int i = tid >> 3, l = tid & 7;

    float4 be = ((const float4*)(bg2 + (size_t)i * 64))[l];
    float4 ga = ((const float4*)(bg2 + (size_t)i * 64 + 32))[l];

    int base = starts[i], deg = cnt[i];
    float4 a0 = make_float4(0.f, 0.f, 0.f, 0.f);
    float4 a1 = make_float4(0.f, 0.f, 0.f, 0.f);
    int e = 0;
    for (; e + 1 < deg; e += 2) {
        int s0 = csr_src[base + e];
        int s1 = csr_src[base + e + 1];
        ushort4 u = ((const ushort4*)xlb)[(size_t)s0 * 8 + l];
        ushort4 w = ((const ushort4*)xlb)[(size_t)s1 * 8 + l];
        a0.x += fmaxf(fmaf(ga.x, bf2f(u.x), be.x), 0.f);
        a0.y += fmaxf(fmaf(ga.y, bf2f(u.y), be.y), 0.f);
        a0.z += fmaxf(fmaf(ga.z, bf2f(u.z), be.z), 0.f);
        a0.w += fmaxf(fmaf(ga.w, bf2f(u.w), be.w), 0.f);
        a1.x += fmaxf(fmaf(ga.x, bf2f(w.x), be.x), 0.f);
        a1.y += fmaxf(fmaf(ga.y, bf2f(w.y), be.y), 0.f);
        a1.z += fmaxf(fmaf(ga.z, bf2f(w.z), be.z), 0.f);
        a1.w += fmaxf(fmaf(ga.w, bf2f(w.w), be.w), 0.f);
    }
    if (e < deg) {
        int s0 = csr_src[base + e];
        ushort4 u = ((const ushort4*)xlb)[(size_t)s0 * 8 + l];
        a0.x += fmaxf(fmaf(ga.x, bf2f(u.x), be.x), 0.f);
        a0.y += fmaxf(fmaf(ga.y, bf2f(u.y), be.y), 0.f);
        a0.z += fmaxf(fmaf(ga.z, bf2f(u.z), be.z), 0.f);
        a0.w += fmaxf(fmaf(ga.w, bf2f(u.w), be.w), 0.f);
    }
    float inv = 1.0f / fmaxf((float)deg, 1.0f);
    float4 sk = ((const float4*)(skip2 + (size_t)i * 32))[l];
    float4 o = make_float4(fmaxf(fmaf(a0.x + a1.x, inv, sk.x), 0.f),
                           fmaxf(fmaf(a0.y + a1.y, inv, sk.y), 0.f),
                           fmaxf(fmaf(a0.z + a1.z, inv, sk.z), 0.f),
                           fmaxf(fmaf(a0.w + a1.w, inv, sk.w), 0.f));
    ((float4*)(h2 + (size_t)i * 32))[l] = o;
}

// ======================= Layer 3 node-side (q,v stored interleaved bf16) =======================
__global__ __launch_bounds__(256) void k_node3(
    const float* __restrict__ h2,
    const float* __restrict__ Wk, const float* __restrict__ bk,
    const float* __restrict__ Wq, const float* __restrict__ bq,
    const float* __restrict__ Wv, const float* __restrict__ bv,
    const float* __restrict__ Wskip, const float* __restrict__ b,
    float* __restrict__ k3, u16* __restrict__ qvb, float* __restrict__ acc3)
{
    __shared__ float sWk[1024], sWq[1024], sWv[1024], sWs[1024];
    int t = threadIdx.x;
    for (int idx = t; idx < 1024; idx += 256) {
        sWk[idx] = Wk[idx];
        sWq[idx] = Wq[idx];
        sWv[idx] = Wv[idx];
        sWs[idx] = Wskip[idx];
    }
    __syncthreads();

    int tid = blockIdx.x * 256 + t;
    if (tid >= N_NODES * 8) return;
    int i = tid >> 3, l = tid & 7;

    float h[32];
    const float4* hp = (const float4*)(h2 + (size_t)i * 32);
#pragma unroll
    for (int j = 0; j < 8; j++) {
        float4 v = hp[j];
        h[4 * j + 0] = v.x; h[4 * j + 1] = v.y;
        h[4 * j + 2] = v.z; h[4 * j + 3] = v.w;
    }

    float4 bk4 = ((const float4*)bk)[l];
    float4 bq4 = ((const float4*)bq)[l];
    float4 bv4 = ((const float4*)bv)[l];
    float4 bb4 = ((const float4*)b)[l];

    float4 kk = dot4(h, sWk + l * 4, 32);
    kk.x += bk4.x; kk.y += bk4.y; kk.z += bk4.z; kk.w += bk4.w;
    ((float4*)(k3 + (size_t)i * 32))[l] = kk;

    float4 qq = dot4(h, sWq + l * 4, 32);
    qq.x += bq4.x; qq.y += bq4.y; qq.z += bq4.z; qq.w += bq4.w;
    float4 vv = dot4(h, sWv + l * 4, 32);
    vv.x += bv4.x; vv.y += bv4.y; vv.z += bv4.z; vv.w += bv4.w;

    // lane chunk: [q0|q1, q2|q3, v0|v1, v2|v3] as packed bf16 pairs (16 B)
    // node i occupies uint4 indices [i*8, i*8+8)  -- 8 lanes x 16 B = 128 B
    uint4 pk;
    pk.x = (u32)f2bf(qq.x) | ((u32)f2bf(qq.y) << 16);
    pk.y = (u32)f2bf(qq.z) | ((u32)f2bf(qq.w) << 16);
    pk.z = (u32)f2bf(vv.x) | ((u32)f2bf(vv.y) << 16);
    pk.w = (u32)f2bf(vv.z) | ((u32)f2bf(vv.w) << 16);
    ((uint4*)qvb)[(size_t)i * 8 + l] = pk;

    float4 ss = dot4(h, sWs + l * 4, 32);
    ss.x += bb4.x; ss.y += bb4.y; ss.z += bb4.z; ss.w += bb4.w;
    ((float4*)(acc3 + (size_t)i * 32))[l] = ss;
}

// ResGated gather: acc3 += sum sigm(k3_i + q_s) * v_s, q/v packed bf16
__global__ __launch_bounds__(256) void k_gath3(
    const int* __restrict__ csr_src, const int* __restrict__ starts,
    const int* __restrict__ cnt,
    const float* __restrict__ k3, const u16* __restrict__ qvb,
    float* __restrict__ acc3)
{
    int tid = blockIdx.x * 256 + threadIdx.x;
    if (tid >= N_NODES * 8) return;
    int i = tid >> 3, l = tid & 7;

    float4 kk = ((const float4*)(k3 + (size_t)i * 32))[l];
    int base = starts[i], deg = cnt[i];
    float4 a0 = make_float4(0.f, 0.f, 0.f, 0.f);
    float4 a1 = make_float4(0.f, 0.f, 0.f, 0.f);
    int e = 0;
    for (; e + 1 < deg; e += 2) {
        int s0 = csr_src[base + e];
        int s1 = csr_src[base + e + 1];
        uint4 p0 = ((const uint4*)qvb)[(size_t)s0 * 8 + l];
        uint4 p1 = ((const uint4*)qvb)[(size_t)s1 * 8 + l];
        a0.x += sigm(kk.x + bf2f((u16)p0.x)) * bf2f((u16)p0.z);
        a0.y += sigm(kk.y + bf2f((u16)(p0.x >> 16))) * bf2f((u16)(p0.z >> 16));
        a0.z += sigm(kk.z + bf2f((u16)p0.y)) * bf2f((u16)p0.w);
        a0.w += sigm(kk.w + bf2f((u16)(p0.y >> 16))) * bf2f((u16)(p0.w >> 16));
        a1.x += sigm(kk.x + bf2f((u16)p1.x)) * bf2f((u16)p1.z);
        a1.y += sigm(kk.y + bf2f((u16)(p1.x >> 16))) * bf2f((u16)(p1.z >> 16));
        a1.z += sigm(kk.z + bf2f((u16)p1.y)) * bf2f((u16)p1.w);
        a1.w += sigm(kk.w + bf2f((u16)(p1.y >> 16))) * bf2f((u16)(p1.w >> 16));
    }
    if (e < deg) {
        int s0 = csr_src[base + e];
        uint4 p0 = ((const uint4*)qvb)[(size_t)s0 * 8 + l];
        a0.x += sigm(kk.x + bf2f((u16)p0.x)) * bf2f((u16)p0.z);
        a0.y += sigm(kk.y + bf2f((u16)(p0.x >> 16))) * bf2f((u16)(p0.z >> 16));
        a0.z += sigm(kk.z + bf2f((u16)p0.y)) * bf2f((u16)p0.w);
        a0.w += sigm(kk.w + bf2f((u16)(p0.y >> 16))) * bf2f((u16)(p0.w >> 16));
    }
    float4* op = (float4*)(acc3 + (size_t)i * 32) + l;
    float4 cur = *op;
    cur.x += a0.x + a1.x;
    cur.y += a0.y + a1.y;
    cur.z += a0.z + a1.z;
    cur.w += a0.w + a1.w;
    *op = cur;
}

// ======================= pool =======================
__global__ __launch_bounds__(256) void k_gstart(const int* __restrict__ batch,
                                                int* __restrict__ gstart)
{
    int g = blockIdx.x * 256 + threadIdx.x;
    if (g > N_GRAPH) return;
    int lo = 0, hi = N_NODES;
    while (lo < hi) {
        int mid = (lo + hi) >> 1;
        if (batch[mid] < g) lo = mid + 1; else hi = mid;
    }
    gstart[g] = lo;
}

__global__ __launch_bounds__(256) void k_pool(
    const float* __restrict__ h3, const int* __restrict__ gstart,
    float* __restrict__ gmean)
{
    int tid = blockIdx.x * 256 + threadIdx.x;
    int g = tid >> 6;
    if (g >= N_GRAPH) return;
    int lane = tid & 63;
    int sub = lane >> 3, fg = lane & 7;
    int gs = gstart[g], ge = gstart[g + 1];

    float4 a = make_float4(0.f, 0.f, 0.f, 0.f);
    for (int j = gs + sub; j < ge; j += 8) {
        float4 v = ((const float4*)(h3 + (size_t)j * 32))[fg];
        a.x += v.x; a.y += v.y; a.z += v.z; a.w += v.w;
    }
#pragma unroll
    for (int off = 8; off < 64; off <<= 1) {
        a.x += __shfl_xor(a.x, off);
        a.y += __shfl_xor(a.y, off);
        a.z += __shfl_xor(a.z, off);
        a.w += __shfl_xor(a.w, off);
    }
    if (sub == 0) {
        float inv = 1.0f / fmaxf((float)(ge - gs), 1.0f);
        a.x *= inv; a.y *= inv; a.z *= inv; a.w *= inv;
        ((float4*)(gmean + (size_t)g * 32))[fg] = a;
    }
}

__global__ __launch_bounds__(256) void k_final(
    const float* __restrict__ gmean,
    const float* __restrict__ linW, const float* __restrict__ linb,
    float* __restrict__ out)
{
    int tid = blockIdx.x * 256 + threadIdx.x;
    if (tid >= N_GRAPH * 10) return;
    int g = tid / 10, c = tid % 10;
    const float* gr = gmean + (size_t)g * 32;
    float a = 0.f;
#pragma unroll
    for (int k = 0; k < 32; k++) a = fmaf(gr[k], linW[k * 10 + c], a);
    out[tid] = a + linb[c];
}

extern "C" void kernel_launch(void* const* d_in, const int* in_sizes, int n_in,
                              void* d_out, int out_size, void* d_ws, size_t ws_size,
                              hipStream_t stream)
{
    const float* x      = (const float*)d_in[0];
    const int*   ei     = (const int*)d_in[1];
    const int*   batch  = (const int*)d_in[2];
    const float* c1_Wk   = (const float*)d_in[4];
    const float* c1_bk   = (const float*)d_in[5];
    const float* c1_Wq   = (const float*)d_in[6];
    const float* c1_bq   = (const float*)d_in[7];
    const float* c1_Wv   = (const float*)d_in[8];
    const float* c1_bv   = (const float*)d_in[9];
    const float* c1_Wsk  = (const float*)d_in[10];
    const float* c1_b    = (const float*)d_in[11];
    const float* c2_Wlin = (const float*)d_in[12];
    const float* c2_Wfilm= (const float*)d_in[13];
    const float* c2_bfilm= (const float*)d_in[14];
    const float* c2_Wls  = (const float*)d_in[15];
    const float* c2_Wfs  = (const float*)d_in[16];
    const float* c3_Wk   = (const float*)d_in[17];
    const float* c3_bk   = (const float*)d_in[18];
    const float* c3_Wq   = (const float*)d_in[19];
    const float* c3_bq   = (const float*)d_in[20];
    const float* c3_Wv   = (const float*)d_in[21];
    const float* c3_bv   = (const float*)d_in[22];
    const float* c3_Wsk  = (const float*)d_in[23];
    const float* c3_b    = (const float*)d_in[24];
    const float* lin_W   = (const float*)d_in[25];
    const float* lin_b   = (const float*)d_in[26];
    float* out = (float*)d_out;

    const size_t N = N_NODES;

    // ---- workspace layout ----
    int* gcnt    = (int*)d_ws;              // 256 (zeroed)
    int* bbase   = gcnt + 256;              // 256
    int* igstart = bbase + 256;             // 1056
    int* bucketed= igstart + 1056;          // NB*BCAP = 2,007,040
    int* icsr    = bucketed + NB * BCAP;    // E
    int* istarts = icsr + N_EDGES;          // N
    int* icnt    = istarts + N;             // N
    float* fbase = (float*)(icnt + N);      // 16B-aligned
    float* h1    = fbase;                   // N*32 (reused as h2)
    float* skip2 = h1 + N * 32;             // N*32 (reused as k3)
    float* bg2   = skip2 + N * 32;          // N*64 (lower half reused as qvb bf16, upper as acc3)
    u16*   xlb   = (u16*)(bg2 + N * 64);    // N*32 bf16
    float* gmean = (float*)(xlb + N * 32);  // G*32

    hipMemsetAsync(gcnt, 0, 256 * sizeof(int), stream);

    const int TB = 256;
    int gPart  = (N_EDGES + 256 * PEPT - 1) / (256 * PEPT);  // 391
    int gNode8 = (N_NODES * 8 + TB - 1) / TB;                // 3125
    int gFin   = (N_GRAPH * 10 + TB - 1) / TB;               // 40

    // CSR build (two-level, LDS-local)
    k_partition<<<gPart, TB, 0, stream>>>(ei, gcnt, bucketed);
    k_bscan<<<1, 256, 0, stream>>>(gcnt, bbase);
    k_place<<<NB, 512, 0, stream>>>(bucketed, gcnt, bbase, icsr, istarts, icnt);
    k_gstart<<<5, TB, 0, stream>>>(batch, igstart);

    // Layer 1
    k_gath1<<<gNode8, TB, 0, stream>>>(x, icsr, istarts, icnt,
                                       c1_Wk, c1_bk, c1_Wq, c1_bq,
                                       c1_Wv, c1_bv, c1_Wsk, c1_b, h1);
    // Layer 2 (FiLM)
    k_node2<<<gNode8, TB, 0, stream>>>(h1, c2_Wlin, c2_Wfilm, c2_bfilm,
                                       c2_Wls, c2_Wfs, skip2, bg2, xlb);
    float* h2 = h1;
    k_gath2<<<gNode8, TB, 0, stream>>>(icsr, istarts, icnt, bg2, xlb, skip2, h2);
    // Layer 3 (ResGated)
    float* k3   = skip2;
    u16*   qvb  = (u16*)bg2;
    float* acc3 = bg2 + N * 32;
    k_node3<<<gNode8, TB, 0, stream>>>(h2, c3_Wk, c3_bk, c3_Wq, c3_bq,
                                       c3_Wv, c3_bv, c3_Wsk, c3_b,
                                       k3, qvb, acc3);
    k_gath3<<<gNode8, TB, 0, stream>>>(icsr, istarts, icnt, k3, qvb, acc3);
    // Pool + classifier
    k_pool<<<256, TB, 0, stream>>>(acc3, igstart, gmean);
    k_final<<<gFin, TB, 0, stream>>>(gmean, lin_W, lin_b, out);
}